// Round 2
// baseline (344.370 us; speedup 1.0000x reference)
//
#include <hip/hip_runtime.h>
#include <math.h>

#define RED_BLOCKS 1024
#define RED_THREADS 256
#define EVAL_THREADS 256

// ws float layout (params = ws[0..63]):
//   [0] x_min
//   [1] 1/(x_max - x_min + 1e-8)
//   [2] t[4]   (first inner knot boundary, 1/3)
//   [3] t[5]   (second inner knot boundary, 2/3)
//   [8 + kk*12 + 0..5]  window W: t[k-2 .. k+3] for k = 3+kk
//   [8 + kk*12 + 6..11] reciprocal denominators r10,r20,r21,r30,r31,r32
//   [64..64+RED_BLOCKS)              block mins
//   [64+RED_BLOCKS..64+2*RED_BLOCKS) block maxs

__global__ void reduce_minmax_kernel(const float* __restrict__ x, int n,
                                     float* __restrict__ bmin,
                                     float* __restrict__ bmax) {
    float lmin = INFINITY, lmax = -INFINITY;
    int tid = blockIdx.x * blockDim.x + threadIdx.x;
    int stride = gridDim.x * blockDim.x;
    int n4 = n >> 2;
    const float4* x4 = reinterpret_cast<const float4*>(x);
    for (int i = tid; i < n4; i += stride) {
        float4 v = x4[i];
        lmin = fminf(lmin, fminf(fminf(v.x, v.y), fminf(v.z, v.w)));
        lmax = fmaxf(lmax, fmaxf(fmaxf(v.x, v.y), fmaxf(v.z, v.w)));
    }
    for (int i = (n4 << 2) + tid; i < n; i += stride) {
        float v = x[i];
        lmin = fminf(lmin, v);
        lmax = fmaxf(lmax, v);
    }
#pragma unroll
    for (int off = 32; off > 0; off >>= 1) {
        lmin = fminf(lmin, __shfl_down(lmin, off));
        lmax = fmaxf(lmax, __shfl_down(lmax, off));
    }
    __shared__ float smin[RED_THREADS / 64], smax[RED_THREADS / 64];
    int wave = threadIdx.x >> 6;
    if ((threadIdx.x & 63) == 0) { smin[wave] = lmin; smax[wave] = lmax; }
    __syncthreads();
    if (threadIdx.x == 0) {
        float m = smin[0], M = smax[0];
#pragma unroll
        for (int w = 1; w < RED_THREADS / 64; ++w) {
            m = fminf(m, smin[w]);
            M = fmaxf(M, smax[w]);
        }
        bmin[blockIdx.x] = m;
        bmax[blockIdx.x] = M;
    }
}

__global__ void finalize_kernel(const float* __restrict__ bmin,
                                const float* __restrict__ bmax, int nb,
                                const float* __restrict__ knots,
                                float* __restrict__ params) {
    float lmin = INFINITY, lmax = -INFINITY;
    for (int i = threadIdx.x; i < nb; i += blockDim.x) {
        lmin = fminf(lmin, bmin[i]);
        lmax = fmaxf(lmax, bmax[i]);
    }
#pragma unroll
    for (int off = 32; off > 0; off >>= 1) {
        lmin = fminf(lmin, __shfl_down(lmin, off));
        lmax = fmaxf(lmax, __shfl_down(lmax, off));
    }
    __shared__ float smin[4], smax[4];
    int wave = threadIdx.x >> 6;
    if ((threadIdx.x & 63) == 0) { smin[wave] = lmin; smax[wave] = lmax; }
    __syncthreads();
    if (threadIdx.x == 0) {
        float m = smin[0], M = smax[0];
#pragma unroll
        for (int w = 1; w < 4; ++w) {
            m = fminf(m, smin[w]);
            M = fmaxf(M, smax[w]);
        }
        float t[10];
#pragma unroll
        for (int j = 0; j < 10; ++j) t[j] = knots[j];
        params[0] = m;
        params[1] = 1.0f / (M - m + 1e-8f);
        params[2] = t[4];
        params[3] = t[5];
        for (int kk = 0; kk < 3; ++kk) {
            int k = 3 + kk;
            int base = 8 + kk * 12;
            for (int i = 0; i < 6; ++i) params[base + i] = t[k - 2 + i];
            float d10 = t[k + 1] - t[k];
            float d20 = t[k + 1] - t[k - 1];
            float d21 = t[k + 2] - t[k];
            float d30 = t[k + 1] - t[k - 2];
            float d31 = t[k + 2] - t[k - 1];
            float d32 = t[k + 3] - t[k];
            params[base + 6]  = (d10 > 0.0f) ? 1.0f / d10 : 0.0f;
            params[base + 7]  = (d20 > 0.0f) ? 1.0f / d20 : 0.0f;
            params[base + 8]  = (d21 > 0.0f) ? 1.0f / d21 : 0.0f;
            params[base + 9]  = (d30 > 0.0f) ? 1.0f / d30 : 0.0f;
            params[base + 10] = (d31 > 0.0f) ? 1.0f / d31 : 0.0f;
            params[base + 11] = (d32 > 0.0f) ? 1.0f / d32 : 0.0f;
        }
    }
}

// Localized de Boor: only 4 nonzero cubic bases; scatter into 6 slots.
__device__ __forceinline__ void eval6(float u, float t4, float t5,
                                      const float W[3][12],
                                      float* __restrict__ o) {
    const bool c1 = (u >= t4);
    const bool c2 = (u >= t5);
#define SELW(i) (c2 ? W[2][i] : (c1 ? W[1][i] : W[0][i]))
    float w0 = SELW(0), w1 = SELW(1), w2 = SELW(2);
    float w3 = SELW(3), w4 = SELW(4), w5 = SELW(5);
    float r10 = SELW(6), r20 = SELW(7), r21 = SELW(8);
    float r30 = SELW(9), r31 = SELW(10), r32 = SELW(11);
#undef SELW
    float left1 = u - w2, left2 = u - w1, left3 = u - w0;
    float right1 = w3 - u, right2 = w4 - u, right3 = w5 - u;
    // j = 1
    float temp = r10;                 // N0(=1) * r10
    float N0 = right1 * temp;
    float N1 = left1 * temp;
    // j = 2
    temp = N0 * r20;
    N0 = right1 * temp;
    float saved = left2 * temp;
    temp = N1 * r21;
    N1 = fmaf(right2, temp, saved);
    float N2 = left1 * temp;
    // j = 3
    temp = N0 * r30;
    N0 = right1 * temp;
    saved = left3 * temp;
    temp = N1 * r31;
    N1 = fmaf(right2, temp, saved);
    saved = left2 * temp;
    temp = N2 * r32;
    N2 = fmaf(right3, temp, saved);
    float N3 = left1 * temp;
    // scatter: nonzero slots are [kk .. kk+3], kk = c1 + c2
    o[0] = c1 ? 0.0f : N0;
    o[1] = c2 ? 0.0f : (c1 ? N0 : N1);
    o[2] = c2 ? N0 : (c1 ? N1 : N2);
    o[3] = c2 ? N1 : (c1 ? N2 : N3);
    o[4] = c2 ? N2 : (c1 ? N3 : 0.0f);
    o[5] = c2 ? N3 : 0.0f;
}

__global__ void eval_kernel(const float* __restrict__ x,
                            const float* __restrict__ params,
                            float* __restrict__ out, int n) {
    const float xmin = params[0];
    const float invd = params[1];
    const float t4 = params[2];
    const float t5 = params[3];
    float W[3][12];
#pragma unroll
    for (int kk = 0; kk < 3; ++kk)
#pragma unroll
        for (int i = 0; i < 12; ++i) W[kk][i] = params[8 + kk * 12 + i];

    int q = blockIdx.x * blockDim.x + threadIdx.x;
    int nquad = n >> 2;
    if (q < nquad) {
        float4 v = reinterpret_cast<const float4*>(x)[q];
        float o[24];
        eval6((v.x - xmin) * invd, t4, t5, W, o + 0);
        eval6((v.y - xmin) * invd, t4, t5, W, o + 6);
        eval6((v.z - xmin) * invd, t4, t5, W, o + 12);
        eval6((v.w - xmin) * invd, t4, t5, W, o + 18);
        float4* o4 = reinterpret_cast<float4*>(out) + (size_t)q * 6;
#pragma unroll
        for (int s = 0; s < 6; ++s)
            o4[s] = make_float4(o[4 * s], o[4 * s + 1], o[4 * s + 2], o[4 * s + 3]);
    }
    // tail (n not divisible by 4)
    if (q == 0) {
        for (int i = nquad << 2; i < n; ++i) {
            float o[6];
            eval6((x[i] - xmin) * invd, t4, t5, W, o);
#pragma unroll
            for (int k = 0; k < 6; ++k) out[(size_t)i * 6 + k] = o[k];
        }
    }
}

extern "C" void kernel_launch(void* const* d_in, const int* in_sizes, int n_in,
                              void* d_out, int out_size, void* d_ws, size_t ws_size,
                              hipStream_t stream) {
    const float* x = (const float*)d_in[0];
    const float* knots = (const float*)d_in[1];
    float* out = (float*)d_out;
    int n = in_sizes[0];

    float* wsf = (float*)d_ws;
    float* params = wsf;                 // 64 floats reserved
    float* bmin = wsf + 64;              // RED_BLOCKS floats
    float* bmax = wsf + 64 + RED_BLOCKS; // RED_BLOCKS floats

    reduce_minmax_kernel<<<RED_BLOCKS, RED_THREADS, 0, stream>>>(x, n, bmin, bmax);
    finalize_kernel<<<1, 256, 0, stream>>>(bmin, bmax, RED_BLOCKS, knots, params);
    int nquad = n >> 2;
    int eval_blocks = (nquad + EVAL_THREADS - 1) / EVAL_THREADS;
    if (eval_blocks < 1) eval_blocks = 1;
    eval_kernel<<<eval_blocks, EVAL_THREADS, 0, stream>>>(x, params, out, n);
}

// Round 3
// 328.089 us; speedup vs baseline: 1.0496x; 1.0496x over previous
//
#include <hip/hip_runtime.h>
#include <math.h>

#define RED_BLOCKS 1024
#define RED_THREADS 256
#define EVAL_THREADS 256
#define PTS_PER_THREAD 4
#define PTS_PER_BLOCK (EVAL_THREADS * PTS_PER_THREAD)   // 1024 points
#define OUT4_PER_BLOCK (PTS_PER_BLOCK * 6 / 4)          // 1536 float4s

// ws float layout (params = ws[0..63]):
//   [0] x_min
//   [1] 1/(x_max - x_min + 1e-8)
//   [2] t[4]   (first inner knot boundary, 1/3)
//   [3] t[5]   (second inner knot boundary, 2/3)
//   [8 + kk*12 + 0..5]  window W: t[k-2 .. k+3] for k = 3+kk
//   [8 + kk*12 + 6..11] reciprocal denominators r10,r20,r21,r30,r31,r32
//   [64..64+RED_BLOCKS)              block mins
//   [64+RED_BLOCKS..64+2*RED_BLOCKS) block maxs

__global__ void reduce_minmax_kernel(const float* __restrict__ x, int n,
                                     float* __restrict__ bmin,
                                     float* __restrict__ bmax) {
    float lmin = INFINITY, lmax = -INFINITY;
    int tid = blockIdx.x * blockDim.x + threadIdx.x;
    int stride = gridDim.x * blockDim.x;
    int n4 = n >> 2;
    const float4* x4 = reinterpret_cast<const float4*>(x);
    for (int i = tid; i < n4; i += stride) {
        float4 v = x4[i];
        lmin = fminf(lmin, fminf(fminf(v.x, v.y), fminf(v.z, v.w)));
        lmax = fmaxf(lmax, fmaxf(fmaxf(v.x, v.y), fmaxf(v.z, v.w)));
    }
    for (int i = (n4 << 2) + tid; i < n; i += stride) {
        float v = x[i];
        lmin = fminf(lmin, v);
        lmax = fmaxf(lmax, v);
    }
#pragma unroll
    for (int off = 32; off > 0; off >>= 1) {
        lmin = fminf(lmin, __shfl_down(lmin, off));
        lmax = fmaxf(lmax, __shfl_down(lmax, off));
    }
    __shared__ float smin[RED_THREADS / 64], smax[RED_THREADS / 64];
    int wave = threadIdx.x >> 6;
    if ((threadIdx.x & 63) == 0) { smin[wave] = lmin; smax[wave] = lmax; }
    __syncthreads();
    if (threadIdx.x == 0) {
        float m = smin[0], M = smax[0];
#pragma unroll
        for (int w = 1; w < RED_THREADS / 64; ++w) {
            m = fminf(m, smin[w]);
            M = fmaxf(M, smax[w]);
        }
        bmin[blockIdx.x] = m;
        bmax[blockIdx.x] = M;
    }
}

__global__ void finalize_kernel(const float* __restrict__ bmin,
                                const float* __restrict__ bmax, int nb,
                                const float* __restrict__ knots,
                                float* __restrict__ params) {
    float lmin = INFINITY, lmax = -INFINITY;
    for (int i = threadIdx.x; i < nb; i += blockDim.x) {
        lmin = fminf(lmin, bmin[i]);
        lmax = fmaxf(lmax, bmax[i]);
    }
#pragma unroll
    for (int off = 32; off > 0; off >>= 1) {
        lmin = fminf(lmin, __shfl_down(lmin, off));
        lmax = fmaxf(lmax, __shfl_down(lmax, off));
    }
    __shared__ float smin[4], smax[4];
    int wave = threadIdx.x >> 6;
    if ((threadIdx.x & 63) == 0) { smin[wave] = lmin; smax[wave] = lmax; }
    __syncthreads();
    if (threadIdx.x == 0) {
        float m = smin[0], M = smax[0];
#pragma unroll
        for (int w = 1; w < 4; ++w) {
            m = fminf(m, smin[w]);
            M = fmaxf(M, smax[w]);
        }
        float t[10];
#pragma unroll
        for (int j = 0; j < 10; ++j) t[j] = knots[j];
        params[0] = m;
        params[1] = 1.0f / (M - m + 1e-8f);
        params[2] = t[4];
        params[3] = t[5];
        for (int kk = 0; kk < 3; ++kk) {
            int k = 3 + kk;
            int base = 8 + kk * 12;
            for (int i = 0; i < 6; ++i) params[base + i] = t[k - 2 + i];
            float d10 = t[k + 1] - t[k];
            float d20 = t[k + 1] - t[k - 1];
            float d21 = t[k + 2] - t[k];
            float d30 = t[k + 1] - t[k - 2];
            float d31 = t[k + 2] - t[k - 1];
            float d32 = t[k + 3] - t[k];
            params[base + 6]  = (d10 > 0.0f) ? 1.0f / d10 : 0.0f;
            params[base + 7]  = (d20 > 0.0f) ? 1.0f / d20 : 0.0f;
            params[base + 8]  = (d21 > 0.0f) ? 1.0f / d21 : 0.0f;
            params[base + 9]  = (d30 > 0.0f) ? 1.0f / d30 : 0.0f;
            params[base + 10] = (d31 > 0.0f) ? 1.0f / d31 : 0.0f;
            params[base + 11] = (d32 > 0.0f) ? 1.0f / d32 : 0.0f;
        }
    }
}

// Localized de Boor: only 4 nonzero cubic bases; scatter into 6 slots.
__device__ __forceinline__ void eval6(float u, float t4, float t5,
                                      const float W[3][12],
                                      float* __restrict__ o) {
    const bool c1 = (u >= t4);
    const bool c2 = (u >= t5);
#define SELW(i) (c2 ? W[2][i] : (c1 ? W[1][i] : W[0][i]))
    float w0 = SELW(0), w1 = SELW(1), w2 = SELW(2);
    float w3 = SELW(3), w4 = SELW(4), w5 = SELW(5);
    float r10 = SELW(6), r20 = SELW(7), r21 = SELW(8);
    float r30 = SELW(9), r31 = SELW(10), r32 = SELW(11);
#undef SELW
    float left1 = u - w2, left2 = u - w1, left3 = u - w0;
    float right1 = w3 - u, right2 = w4 - u, right3 = w5 - u;
    // j = 1
    float temp = r10;                 // N0(=1) * r10
    float N0 = right1 * temp;
    float N1 = left1 * temp;
    // j = 2
    temp = N0 * r20;
    N0 = right1 * temp;
    float saved = left2 * temp;
    temp = N1 * r21;
    N1 = fmaf(right2, temp, saved);
    float N2 = left1 * temp;
    // j = 3
    temp = N0 * r30;
    N0 = right1 * temp;
    saved = left3 * temp;
    temp = N1 * r31;
    N1 = fmaf(right2, temp, saved);
    saved = left2 * temp;
    temp = N2 * r32;
    N2 = fmaf(right3, temp, saved);
    float N3 = left1 * temp;
    // scatter: nonzero slots are [kk .. kk+3], kk = c1 + c2
    o[0] = c1 ? 0.0f : N0;
    o[1] = c2 ? 0.0f : (c1 ? N0 : N1);
    o[2] = c2 ? N0 : (c1 ? N1 : N2);
    o[3] = c2 ? N1 : (c1 ? N2 : N3);
    o[4] = c2 ? N2 : (c1 ? N3 : 0.0f);
    o[5] = c2 ? N3 : 0.0f;
}

__global__ void eval_kernel(const float* __restrict__ x,
                            const float* __restrict__ params,
                            float* __restrict__ out, int n) {
    __shared__ float4 lds4[OUT4_PER_BLOCK];   // 24 KB staging tile

    const float xmin = params[0];
    const float invd = params[1];
    const float t4 = params[2];
    const float t5 = params[3];
    float W[3][12];
#pragma unroll
    for (int kk = 0; kk < 3; ++kk)
#pragma unroll
        for (int i = 0; i < 12; ++i) W[kk][i] = params[8 + kk * 12 + i];

    const int tid = threadIdx.x;
    const int full_blocks = n / PTS_PER_BLOCK;

    if ((int)blockIdx.x < full_blocks) {
        // ---- main path: 4 points/thread, LDS-transposed coalesced stores ----
        int q = blockIdx.x * EVAL_THREADS + tid;       // float4 index into x
        float4 v = reinterpret_cast<const float4*>(x)[q];
        float o[24];
        eval6((v.x - xmin) * invd, t4, t5, W, o + 0);
        eval6((v.y - xmin) * invd, t4, t5, W, o + 6);
        eval6((v.z - xmin) * invd, t4, t5, W, o + 12);
        eval6((v.w - xmin) * invd, t4, t5, W, o + 18);
#pragma unroll
        for (int k = 0; k < 6; ++k)
            lds4[tid * 6 + k] =
                make_float4(o[4 * k], o[4 * k + 1], o[4 * k + 2], o[4 * k + 3]);
        __syncthreads();
        // coalesced writeback: each wave-instruction writes 1 KB contiguous,
        // full 128B lines -> no partial-line RMW at L2/HBM
        float4* out4 = reinterpret_cast<float4*>(out) +
                       (size_t)blockIdx.x * OUT4_PER_BLOCK;
#pragma unroll
        for (int s = 0; s < 6; ++s)
            out4[s * EVAL_THREADS + tid] = lds4[s * EVAL_THREADS + tid];
    } else {
        // ---- tail path: remaining n % 1024 points, scalar stores ----
        for (int p = full_blocks * PTS_PER_BLOCK + tid; p < n; p += EVAL_THREADS) {
            float o[6];
            eval6((x[p] - xmin) * invd, t4, t5, W, o);
#pragma unroll
            for (int k = 0; k < 6; ++k) out[(size_t)p * 6 + k] = o[k];
        }
    }
}

extern "C" void kernel_launch(void* const* d_in, const int* in_sizes, int n_in,
                              void* d_out, int out_size, void* d_ws, size_t ws_size,
                              hipStream_t stream) {
    const float* x = (const float*)d_in[0];
    const float* knots = (const float*)d_in[1];
    float* out = (float*)d_out;
    int n = in_sizes[0];

    float* wsf = (float*)d_ws;
    float* params = wsf;                 // 64 floats reserved
    float* bmin = wsf + 64;              // RED_BLOCKS floats
    float* bmax = wsf + 64 + RED_BLOCKS; // RED_BLOCKS floats

    reduce_minmax_kernel<<<RED_BLOCKS, RED_THREADS, 0, stream>>>(x, n, bmin, bmax);
    finalize_kernel<<<1, 256, 0, stream>>>(bmin, bmax, RED_BLOCKS, knots, params);
    int full_blocks = n / PTS_PER_BLOCK;
    int eval_blocks = full_blocks + ((n % PTS_PER_BLOCK) ? 1 : 0);
    if (eval_blocks < 1) eval_blocks = 1;
    eval_kernel<<<eval_blocks, EVAL_THREADS, 0, stream>>>(x, params, out, n);
}

// Round 5
// 317.294 us; speedup vs baseline: 1.0853x; 1.0340x over previous
//
#include <hip/hip_runtime.h>
#include <math.h>

#define RED_BLOCKS 1024
#define RED_THREADS 256
#define EVAL_THREADS 256
#define PTS_PER_THREAD 4
#define PTS_PER_BLOCK (EVAL_THREADS * PTS_PER_THREAD)   // 1024 points
#define OUT4_PER_BLOCK (PTS_PER_BLOCK * 6 / 4)          // 1536 float4s
// pad: one extra float4 per 8 to break bank-group collisions on the
// point-major writes (write idx = tid*6+k had 4 lanes/bank-group x16)
#define LDSPAD(i) ((i) + ((i) >> 3))
#define LDS4_SIZE (LDSPAD(OUT4_PER_BLOCK - 1) + 1)      // 1728 float4 = 27 KB

// native clang vector type: __builtin_nontemporal_store requires a real
// vector type, HIP's float4 struct is rejected
typedef float floatx4 __attribute__((ext_vector_type(4)));

// ws float layout (params = ws[0..63]):
//   [0] x_min
//   [1] 1/(x_max - x_min + 1e-8)
//   [2] t[4]   [3] t[5]
//   [8 + kk*12 + 0..5]  knot window t[k-2..k+3], k = 3+kk
//   [8 + kk*12 + 6..11] reciprocal denominators r10,r20,r21,r30,r31,r32
//   [64..64+RED_BLOCKS)              block mins
//   [64+RED_BLOCKS..64+2*RED_BLOCKS) block maxs

__global__ void reduce_minmax_kernel(const float* __restrict__ x, int n,
                                     float* __restrict__ bmin,
                                     float* __restrict__ bmax) {
    float lmin = INFINITY, lmax = -INFINITY;
    int tid = blockIdx.x * blockDim.x + threadIdx.x;
    int stride = gridDim.x * blockDim.x;
    int n4 = n >> 2;
    const float4* x4 = reinterpret_cast<const float4*>(x);
    for (int i = tid; i < n4; i += stride) {
        float4 v = x4[i];
        lmin = fminf(lmin, fminf(fminf(v.x, v.y), fminf(v.z, v.w)));
        lmax = fmaxf(lmax, fmaxf(fmaxf(v.x, v.y), fmaxf(v.z, v.w)));
    }
    for (int i = (n4 << 2) + tid; i < n; i += stride) {
        float v = x[i];
        lmin = fminf(lmin, v);
        lmax = fmaxf(lmax, v);
    }
#pragma unroll
    for (int off = 32; off > 0; off >>= 1) {
        lmin = fminf(lmin, __shfl_down(lmin, off));
        lmax = fmaxf(lmax, __shfl_down(lmax, off));
    }
    __shared__ float smin[RED_THREADS / 64], smax[RED_THREADS / 64];
    int wave = threadIdx.x >> 6;
    if ((threadIdx.x & 63) == 0) { smin[wave] = lmin; smax[wave] = lmax; }
    __syncthreads();
    if (threadIdx.x == 0) {
        float m = smin[0], M = smax[0];
#pragma unroll
        for (int w = 1; w < RED_THREADS / 64; ++w) {
            m = fminf(m, smin[w]);
            M = fmaxf(M, smax[w]);
        }
        bmin[blockIdx.x] = m;
        bmax[blockIdx.x] = M;
    }
}

__global__ void finalize_kernel(const float* __restrict__ bmin,
                                const float* __restrict__ bmax, int nb,
                                const float* __restrict__ knots,
                                float* __restrict__ params) {
    float lmin = INFINITY, lmax = -INFINITY;
    for (int i = threadIdx.x; i < nb; i += blockDim.x) {
        lmin = fminf(lmin, bmin[i]);
        lmax = fmaxf(lmax, bmax[i]);
    }
#pragma unroll
    for (int off = 32; off > 0; off >>= 1) {
        lmin = fminf(lmin, __shfl_down(lmin, off));
        lmax = fmaxf(lmax, __shfl_down(lmax, off));
    }
    __shared__ float smin[4], smax[4];
    int wave = threadIdx.x >> 6;
    if ((threadIdx.x & 63) == 0) { smin[wave] = lmin; smax[wave] = lmax; }
    __syncthreads();
    if (threadIdx.x == 0) {
        float m = smin[0], M = smax[0];
#pragma unroll
        for (int w = 1; w < 4; ++w) {
            m = fminf(m, smin[w]);
            M = fmaxf(M, smax[w]);
        }
        float t[10];
#pragma unroll
        for (int j = 0; j < 10; ++j) t[j] = knots[j];
        params[0] = m;
        params[1] = 1.0f / (M - m + 1e-8f);
        params[2] = t[4];
        params[3] = t[5];
        for (int kk = 0; kk < 3; ++kk) {
            int k = 3 + kk;
            int base = 8 + kk * 12;
            for (int i = 0; i < 6; ++i) params[base + i] = t[k - 2 + i];
            float d10 = t[k + 1] - t[k];
            float d20 = t[k + 1] - t[k - 1];
            float d21 = t[k + 2] - t[k];
            float d30 = t[k + 1] - t[k - 2];
            float d31 = t[k + 2] - t[k - 1];
            float d32 = t[k + 3] - t[k];
            params[base + 6]  = (d10 > 0.0f) ? 1.0f / d10 : 0.0f;
            params[base + 7]  = (d20 > 0.0f) ? 1.0f / d20 : 0.0f;
            params[base + 8]  = (d21 > 0.0f) ? 1.0f / d21 : 0.0f;
            params[base + 9]  = (d30 > 0.0f) ? 1.0f / d30 : 0.0f;
            params[base + 10] = (d31 > 0.0f) ? 1.0f / d31 : 0.0f;
            params[base + 11] = (d32 > 0.0f) ? 1.0f / d32 : 0.0f;
        }
    }
}

// Localized de Boor: only 4 nonzero cubic bases; scatter into 6 slots.
__device__ __forceinline__ void eval6(float u, float t4, float t5,
                                      const float W[3][12],
                                      float* __restrict__ o) {
    const bool c1 = (u >= t4);
    const bool c2 = (u >= t5);
#define SELW(i) (c2 ? W[2][i] : (c1 ? W[1][i] : W[0][i]))
    float w0 = SELW(0), w1 = SELW(1), w2 = SELW(2);
    float w3 = SELW(3), w4 = SELW(4), w5 = SELW(5);
    float r10 = SELW(6), r20 = SELW(7), r21 = SELW(8);
    float r30 = SELW(9), r31 = SELW(10), r32 = SELW(11);
#undef SELW
    float left1 = u - w2, left2 = u - w1, left3 = u - w0;
    float right1 = w3 - u, right2 = w4 - u, right3 = w5 - u;
    float temp = r10;
    float N0 = right1 * temp;
    float N1 = left1 * temp;
    temp = N0 * r20;
    N0 = right1 * temp;
    float saved = left2 * temp;
    temp = N1 * r21;
    N1 = fmaf(right2, temp, saved);
    float N2 = left1 * temp;
    temp = N0 * r30;
    N0 = right1 * temp;
    saved = left3 * temp;
    temp = N1 * r31;
    N1 = fmaf(right2, temp, saved);
    saved = left2 * temp;
    temp = N2 * r32;
    N2 = fmaf(right3, temp, saved);
    float N3 = left1 * temp;
    o[0] = c1 ? 0.0f : N0;
    o[1] = c2 ? 0.0f : (c1 ? N0 : N1);
    o[2] = c2 ? N0 : (c1 ? N1 : N2);
    o[3] = c2 ? N1 : (c1 ? N2 : N3);
    o[4] = c2 ? N2 : (c1 ? N3 : 0.0f);
    o[5] = c2 ? N3 : 0.0f;
}

__global__ void eval_kernel(const float* __restrict__ x,
                            const float* __restrict__ params,
                            float* __restrict__ out, int n) {
    __shared__ floatx4 lds4[LDS4_SIZE];   // 27 KB staging tile (padded)

    const float xmin = params[0];
    const float invd = params[1];
    const float t4 = params[2];
    const float t5 = params[3];
    float W[3][12];
#pragma unroll
    for (int kk = 0; kk < 3; ++kk)
#pragma unroll
        for (int i = 0; i < 12; ++i) W[kk][i] = params[8 + kk * 12 + i];

    const int tid = threadIdx.x;
    const int full_blocks = n / PTS_PER_BLOCK;

    if ((int)blockIdx.x < full_blocks) {
        int q = blockIdx.x * EVAL_THREADS + tid;       // float4 index into x
        float4 v = reinterpret_cast<const float4*>(x)[q];
        float o[24];
        eval6((v.x - xmin) * invd, t4, t5, W, o + 0);
        eval6((v.y - xmin) * invd, t4, t5, W, o + 6);
        eval6((v.z - xmin) * invd, t4, t5, W, o + 12);
        eval6((v.w - xmin) * invd, t4, t5, W, o + 18);
#pragma unroll
        for (int k = 0; k < 6; ++k) {
            int idx = tid * 6 + k;
            floatx4 val = {o[4 * k], o[4 * k + 1], o[4 * k + 2], o[4 * k + 3]};
            lds4[LDSPAD(idx)] = val;
        }
        __syncthreads();
        // coalesced nontemporal writeback: 64 lanes x 16B = 1KB contiguous
        // per wave-instruction, 'nt' bypasses L2/L3 allocation so the
        // write-once output stream doesn't churn the cache hierarchy
        floatx4* out4 = reinterpret_cast<floatx4*>(out) +
                        (size_t)blockIdx.x * OUT4_PER_BLOCK;
#pragma unroll
        for (int s = 0; s < 6; ++s) {
            int idx = s * EVAL_THREADS + tid;
            __builtin_nontemporal_store(lds4[LDSPAD(idx)], &out4[idx]);
        }
    } else {
        // tail path: remaining n % 1024 points
        for (int p = full_blocks * PTS_PER_BLOCK + tid; p < n; p += EVAL_THREADS) {
            float o[6];
            eval6((x[p] - xmin) * invd, t4, t5, W, o);
#pragma unroll
            for (int k = 0; k < 6; ++k) out[(size_t)p * 6 + k] = o[k];
        }
    }
}

extern "C" void kernel_launch(void* const* d_in, const int* in_sizes, int n_in,
                              void* d_out, int out_size, void* d_ws, size_t ws_size,
                              hipStream_t stream) {
    const float* x = (const float*)d_in[0];
    const float* knots = (const float*)d_in[1];
    float* out = (float*)d_out;
    int n = in_sizes[0];

    float* wsf = (float*)d_ws;
    float* params = wsf;                 // 64 floats reserved
    float* bmin = wsf + 64;              // RED_BLOCKS floats
    float* bmax = wsf + 64 + RED_BLOCKS; // RED_BLOCKS floats

    reduce_minmax_kernel<<<RED_BLOCKS, RED_THREADS, 0, stream>>>(x, n, bmin, bmax);
    finalize_kernel<<<1, 256, 0, stream>>>(bmin, bmax, RED_BLOCKS, knots, params);
    int full_blocks = n / PTS_PER_BLOCK;
    int eval_blocks = full_blocks + ((n % PTS_PER_BLOCK) ? 1 : 0);
    if (eval_blocks < 1) eval_blocks = 1;
    eval_kernel<<<eval_blocks, EVAL_THREADS, 0, stream>>>(x, params, out, n);
}